// Round 8
// baseline (379.342 us; speedup 1.0000x reference)
//
#include <hip/hip_runtime.h>
#include <hip/hip_fp16.h>

#define NEG_SLOPE 0.2f
#define NRANGE 8          // dst-range partitions == XCD count (b%8 heuristic)
#define SCAN_TILE 2048    // elements per scan block

__device__ __forceinline__ float elu_f(float x) {
    return x > 0.f ? x : __expf(x) - 1.f;
}
__device__ __forceinline__ float lrelu_f(float x) {
    return x > 0.f ? x : NEG_SLOPE * x;
}

// ---------------------------------------------------------------------------
// CSR build step 1: histogram of destination nodes. Plain loads (NOT
// nontemporal): this pass warms L3 with ei so the scatter's 8 range-passes
// are L3-served. (Round-7 lesson: nt hints forced 59 MB of HBM re-reads.)
// ---------------------------------------------------------------------------
__global__ __launch_bounds__(256) void hist_kernel(
    const int* __restrict__ ei, int* __restrict__ cnt, int E)
{
    int t = blockIdx.x * 256 + threadIdx.x;
    if (t < E) atomicAdd(&cnt[ei[E + t]], 1);
}

// ---------------------------------------------------------------------------
// Hierarchical scan phase A: per-tile sums.
// ---------------------------------------------------------------------------
__global__ __launch_bounds__(256) void scan_partial_kernel(
    const int* __restrict__ cnt, int* __restrict__ blocksum, int N)
{
    __shared__ int red[256];
    int base = blockIdx.x * SCAN_TILE;
    int s = 0;
#pragma unroll
    for (int k = 0; k < 8; ++k) {
        int i = base + k * 256 + threadIdx.x;
        if (i < N) s += cnt[i];
    }
    red[threadIdx.x] = s;
    __syncthreads();
    for (int off = 128; off; off >>= 1) {
        if (threadIdx.x < off) red[threadIdx.x] += red[threadIdx.x + off];
        __syncthreads();
    }
    if (threadIdx.x == 0) blocksum[blockIdx.x] = red[0];
}

// ---------------------------------------------------------------------------
// Hierarchical scan phase B: exclusive scan of tile sums; rowptr[N]=E.
// ---------------------------------------------------------------------------
__global__ __launch_bounds__(1024) void scan_blocksum_kernel(
    int* __restrict__ blocksum, int nb, int* __restrict__ rowptr, int N, int E)
{
    __shared__ int part[1024];
    int t = threadIdx.x;
    part[t] = (t < nb) ? blocksum[t] : 0;
    __syncthreads();
    for (int off = 1; off < 1024; off <<= 1) {
        int v = (t >= off) ? part[t - off] : 0;
        __syncthreads();
        part[t] += v;
        __syncthreads();
    }
    if (t < nb) blocksum[t] = (t == 0) ? 0 : part[t - 1];  // exclusive
    if (t == 0) rowptr[N] = E;
}

// ---------------------------------------------------------------------------
// Hierarchical scan phase C: tile-local exclusive scan + tile offset;
// writes rowptr and scatter cursor (cursor aliases cnt).
// ---------------------------------------------------------------------------
__global__ __launch_bounds__(256) void scan_final_kernel(
    int* __restrict__ cnt, const int* __restrict__ blocksum,
    int* __restrict__ rowptr, int N)
{
    __shared__ int lds[SCAN_TILE];
    __shared__ int tsum[256];
    int base = blockIdx.x * SCAN_TILE;
    int tid = threadIdx.x;
#pragma unroll
    for (int k = 0; k < 8; ++k) {
        int i = base + k * 256 + tid;
        lds[k * 256 + tid] = (i < N) ? cnt[i] : 0;
    }
    __syncthreads();
    int my[8];
    int s = 0;
#pragma unroll
    for (int j = 0; j < 8; ++j) { my[j] = s; s += lds[tid * 8 + j]; }
    tsum[tid] = s;
    __syncthreads();
    for (int off = 1; off < 256; off <<= 1) {
        int v = (tid >= off) ? tsum[tid - off] : 0;
        __syncthreads();
        tsum[tid] += v;
        __syncthreads();
    }
    int texcl = (tid == 0) ? 0 : tsum[tid - 1];
    int boff = blocksum[blockIdx.x];
    __syncthreads();
#pragma unroll
    for (int j = 0; j < 8; ++j) lds[tid * 8 + j] = boff + texcl + my[j];
    __syncthreads();
#pragma unroll
    for (int k = 0; k < 8; ++k) {
        int i = base + k * 256 + tid;
        if (i < N) {
            int v = lds[k * 256 + tid];
            rowptr[i] = v;
            cnt[i] = v;      // scatter cursor
        }
    }
}

// ---------------------------------------------------------------------------
// CSR scatter, standalone (unfused from gemm1 so gemm1's 19 MB of streaming
// doesn't evict the per-XCD srclist write slices from L2). XCD-range-affine
// via b%8; per-node cursors (round-4 lesson: coarse cursors serialize).
// Plain loads: passes 2-8 of the dst column are L3-served.
// ---------------------------------------------------------------------------
__global__ __launch_bounds__(256) void scatter_kernel(
    const int* __restrict__ ei, int* __restrict__ cursor,
    unsigned short* __restrict__ srclist, int E, int N, int nChunks)
{
    int b = blockIdx.x;
    int range = b & (NRANGE - 1);
    int chunk = b >> 3;
    int RS = (N + NRANGE - 1) / NRANGE;
    int lo = range * RS;
    unsigned span = (unsigned)(((lo + RS) > N ? N : (lo + RS)) - lo);
    int per = (E + nChunks - 1) / nChunks;
    int beg = chunk * per;
    int end = beg + per; if (end > E) end = E;
    for (int i = beg + (int)threadIdx.x; i < end; i += 256) {
        int dst = ei[E + i];
        if ((unsigned)(dst - lo) < span) {
            int src = ei[i];
            int pos = atomicAdd(&cursor[dst], 1);
            srclist[pos] = (unsigned short)src;
        }
    }
}

// ---------------------------------------------------------------------------
// GEMM1: h1 = x @ W1 ([N,64]x[64,64]) + fused alpha_src1/alpha_dst1.
// h1 stored fp16 (halves agg1 gather bytes); alpha sums from fp32 acc.
// ---------------------------------------------------------------------------
__global__ __launch_bounds__(256) void gemm1_kernel(
    const float* __restrict__ x, const float* __restrict__ W,
    const float* __restrict__ a_src, const float* __restrict__ a_dst,
    __half* __restrict__ h1, float* __restrict__ as1, float* __restrict__ ad1,
    int N)
{
    __shared__ float Wl[64 * 64];
    __shared__ float Xl[4][64];
    int tid = threadIdx.x;
    for (int i = tid; i < 64 * 64; i += 256) Wl[i] = W[i];
    int r   = tid >> 6;
    int col = tid & 63;
    int row = blockIdx.x * 4 + r;
    if (row < N) Xl[r][col] = x[(size_t)row * 64 + col];
    __syncthreads();
    if (row >= N) return;

    float acc = 0.f;
#pragma unroll
    for (int k = 0; k < 64; ++k) acc += Xl[r][k] * Wl[k * 64 + col];
    h1[(size_t)row * 64 + col] = __float2half(acc);

    int head = col >> 5;
    float ps = acc * a_src[col];
    float pd = acc * a_dst[col];
#pragma unroll
    for (int off = 16; off; off >>= 1) {
        ps += __shfl_xor(ps, off, 32);
        pd += __shfl_xor(pd, off, 32);
    }
    if ((col & 31) == 0) {
        as1[row * 2 + head] = ps;
        ad1[row * 2 + head] = pd;
    }
}

// ---------------------------------------------------------------------------
// Fused layer-1 aggregation + GEMM2 + alpha2. One 64-lane wave per dst node.
// ---------------------------------------------------------------------------
__global__ __launch_bounds__(256) void agg1_gemm2_kernel(
    const int* __restrict__ rowptr, const unsigned short* __restrict__ srclist,
    const __half* __restrict__ h1, const float* __restrict__ as1,
    const float* __restrict__ ad1, const float* __restrict__ b1,
    const float* __restrict__ W2, const float* __restrict__ a_s2,
    const float* __restrict__ a_d2,
    float* __restrict__ h2, float* __restrict__ as2, float* __restrict__ ad2,
    int N)
{
    __shared__ float W2l[64 * 32];
    __shared__ float sh[4][64];
    int tid = threadIdx.x;
    for (int i = tid; i < 64 * 32; i += 256) W2l[i] = W2[i];
    __syncthreads();   // block-uniform

    int n = (blockIdx.x * 256 + tid) >> 6;
    int lane = tid & 63;
    int wid = tid >> 6;
    if (n >= N) return;

    int head = lane >> 5;
    float adn = ad1[n * 2 + head];

    float w = __expf(lrelu_f(as1[n * 2 + head] + adn));
    float den = w;
    float acc = w * __half2float(h1[(size_t)n * 64 + lane]);

    int i = rowptr[n], endp = rowptr[n + 1];
    for (; i + 3 < endp; i += 4) {
        int s0 = srclist[i], s1 = srclist[i + 1];
        int s2 = srclist[i + 2], s3 = srclist[i + 3];
        float a0 = as1[s0 * 2 + head], a1 = as1[s1 * 2 + head];
        float a2 = as1[s2 * 2 + head], a3 = as1[s3 * 2 + head];
        float g0 = __half2float(h1[(size_t)s0 * 64 + lane]);
        float g1 = __half2float(h1[(size_t)s1 * 64 + lane]);
        float g2 = __half2float(h1[(size_t)s2 * 64 + lane]);
        float g3 = __half2float(h1[(size_t)s3 * 64 + lane]);
        float w0 = __expf(lrelu_f(a0 + adn));
        float w1 = __expf(lrelu_f(a1 + adn));
        float w2 = __expf(lrelu_f(a2 + adn));
        float w3 = __expf(lrelu_f(a3 + adn));
        den += (w0 + w1) + (w2 + w3);
        acc += w0 * g0 + w1 * g1 + w2 * g2 + w3 * g3;
    }
    for (; i < endp; ++i) {
        int s0 = srclist[i];
        float w0 = __expf(lrelu_f(as1[s0 * 2 + head] + adn));
        den += w0;
        acc += w0 * __half2float(h1[(size_t)s0 * 64 + lane]);
    }

    float v = elu_f(acc / den + b1[lane]);   // h1e[n, lane]

    // ---- fused GEMM2: h2[n, col] = sum_k h1e[n,k] * W2[k, col] ----
    sh[wid][lane] = v;
    int col = lane & 31;
    int kbase = (lane >> 5) * 32;
    float p = 0.f;
#pragma unroll
    for (int j = 0; j < 32; ++j)
        p += sh[wid][kbase + j] * W2l[(kbase + j) * 32 + col];
    p += __shfl_xor(p, 32, 64);

    if (lane < 32) h2[(size_t)n * 32 + lane] = p;

    float ps = p * a_s2[col];
    float pd = p * a_d2[col];
#pragma unroll
    for (int off = 16; off; off >>= 1) {
        ps += __shfl_xor(ps, off, 32);
        pd += __shfl_xor(pd, off, 32);
    }
    if (lane == 0) { as2[n] = ps; ad2[n] = pd; }
}

// ---------------------------------------------------------------------------
// Layer-2 aggregation + final FC. 32 lanes per dst node, 4x unrolled.
// out layout: [0,N) scores, [N, N+N*32) h
// ---------------------------------------------------------------------------
__global__ __launch_bounds__(256) void agg2_kernel(
    const int* __restrict__ rowptr, const unsigned short* __restrict__ srclist,
    const float* __restrict__ h2, const float* __restrict__ as2,
    const float* __restrict__ ad2, const float* __restrict__ b2,
    const float* __restrict__ fcW, const float* __restrict__ fcb,
    float* __restrict__ out, int N)
{
    int g = blockIdx.x * 256 + threadIdx.x;
    int n = g >> 5;
    int lane = g & 31;
    if (n >= N) return;
    float adn = ad2[n];

    float w = __expf(lrelu_f(as2[n] + adn));
    float den = w;
    float acc = w * h2[(size_t)n * 32 + lane];

    int i = rowptr[n], endp = rowptr[n + 1];
    for (; i + 3 < endp; i += 4) {
        int s0 = srclist[i], s1 = srclist[i + 1];
        int s2 = srclist[i + 2], s3 = srclist[i + 3];
        float a0 = as2[s0], a1 = as2[s1], a2 = as2[s2], a3 = as2[s3];
        float g0 = h2[(size_t)s0 * 32 + lane];
        float g1 = h2[(size_t)s1 * 32 + lane];
        float g2 = h2[(size_t)s2 * 32 + lane];
        float g3 = h2[(size_t)s3 * 32 + lane];
        float w0 = __expf(lrelu_f(a0 + adn));
        float w1 = __expf(lrelu_f(a1 + adn));
        float w2 = __expf(lrelu_f(a2 + adn));
        float w3 = __expf(lrelu_f(a3 + adn));
        den += (w0 + w1) + (w2 + w3);
        acc += w0 * g0 + w1 * g1 + w2 * g2 + w3 * g3;
    }
    for (; i < endp; ++i) {
        int s0 = srclist[i];
        float w0 = __expf(lrelu_f(as2[s0] + adn));
        den += w0;
        acc += w0 * h2[(size_t)s0 * 32 + lane];
    }

    float v = elu_f(acc / den + b2[lane]);
    out[(size_t)N + (size_t)n * 32 + lane] = v;
    float p = v * fcW[lane];
#pragma unroll
    for (int off = 16; off; off >>= 1) p += __shfl_xor(p, off, 32);
    if (lane == 0) out[n] = p + fcb[0];
}

extern "C" void kernel_launch(void* const* d_in, const int* in_sizes, int n_in,
                              void* d_out, int out_size, void* d_ws, size_t ws_size,
                              hipStream_t stream) {
    const float* x    = (const float*)d_in[0];
    const int*   ei   = (const int*)d_in[1];
    const float* W1   = (const float*)d_in[2];
    const float* a_s1 = (const float*)d_in[3];
    const float* a_d1 = (const float*)d_in[4];
    const float* b1   = (const float*)d_in[5];
    const float* W2   = (const float*)d_in[6];
    const float* a_s2 = (const float*)d_in[7];
    const float* a_d2 = (const float*)d_in[8];
    const float* b2   = (const float*)d_in[9];
    const float* fcW  = (const float*)d_in[10];
    const float* fcb  = (const float*)d_in[11];

    const int N = in_sizes[0] / 64;
    const int E = in_sizes[1] / 2;
    const int nScan = (N + SCAN_TILE - 1) / SCAN_TILE;

    // Workspace layout: fp32 arrays, then fp16 h1, then ints, then ushort.
    float* fws  = (float*)d_ws;
    float* as1  = fws;                      // 2N
    float* ad1  = as1 + (size_t)2 * N;      // 2N
    float* as2  = ad1 + (size_t)2 * N;      // N
    float* ad2  = as2 + (size_t)N;          // N
    float* h2   = ad2 + (size_t)N;          // 32N
    __half* h1  = (__half*)(h2 + (size_t)32 * N);   // 64N halves
    int*   cnt     = (int*)(h1 + (size_t)64 * N);   // N (histogram -> cursor)
    int*   rowptr  = cnt + N;                       // N+1
    int*   blocksum = rowptr + N + 1;               // nScan
    unsigned short* srclist = (unsigned short*)(blocksum + nScan);  // E

    hipMemsetAsync(cnt, 0, sizeof(int) * (size_t)N, stream);

    hist_kernel<<<(E + 255) / 256, 256, 0, stream>>>(ei, cnt, E);

    scan_partial_kernel<<<nScan, 256, 0, stream>>>(cnt, blocksum, N);
    scan_blocksum_kernel<<<1, 1024, 0, stream>>>(blocksum, nScan, rowptr, N, E);
    scan_final_kernel<<<nScan, 256, 0, stream>>>(cnt, blocksum, rowptr, N);

    const int nChunks = 256;  // 256 chunks x 8 ranges = 2048 scatter blocks
    scatter_kernel<<<nChunks * NRANGE, 256, 0, stream>>>(ei, cnt, srclist, E, N, nChunks);

    gemm1_kernel<<<(N + 3) / 4, 256, 0, stream>>>(x, W1, a_s1, a_d1, h1, as1, ad1, N);

    agg1_gemm2_kernel<<<((size_t)N * 64 + 255) / 256, 256, 0, stream>>>(
        rowptr, srclist, h1, as1, ad1, b1, W2, a_s2, a_d2, h2, as2, ad2, N);

    agg2_kernel<<<((size_t)N * 32 + 255) / 256, 256, 0, stream>>>(
        rowptr, srclist, h2, as2, ad2, b2, fcW, fcb, (float*)d_out, N);
}

// Round 9
// 370.455 us; speedup vs baseline: 1.0240x; 1.0240x over previous
//
#include <hip/hip_runtime.h>
#include <hip/hip_fp16.h>

#define NEG_SLOPE 0.2f
#define NRANGE 8          // dst-range partitions == XCD count (b%8 heuristic)
#define SCAN_TILE 2048    // elements per scan block

__device__ __forceinline__ float elu_f(float x) {
    return x > 0.f ? x : __expf(x) - 1.f;
}
__device__ __forceinline__ float lrelu_f(float x) {
    return x > 0.f ? x : NEG_SLOPE * x;
}

// ---------------------------------------------------------------------------
// CSR build step 1: histogram of destination nodes. Plain loads: warms L3
// with ei so the scatter's 8 range-passes are L3-served (round-7 lesson).
// ---------------------------------------------------------------------------
__global__ __launch_bounds__(256) void hist_kernel(
    const int* __restrict__ ei, int* __restrict__ cnt, int E)
{
    int t = blockIdx.x * 256 + threadIdx.x;
    if (t < E) atomicAdd(&cnt[ei[E + t]], 1);
}

// ---------------------------------------------------------------------------
// Hierarchical scan phase A: per-tile sums.
// ---------------------------------------------------------------------------
__global__ __launch_bounds__(256) void scan_partial_kernel(
    const int* __restrict__ cnt, int* __restrict__ blocksum, int N)
{
    __shared__ int red[256];
    int base = blockIdx.x * SCAN_TILE;
    int s = 0;
#pragma unroll
    for (int k = 0; k < 8; ++k) {
        int i = base + k * 256 + threadIdx.x;
        if (i < N) s += cnt[i];
    }
    red[threadIdx.x] = s;
    __syncthreads();
    for (int off = 128; off; off >>= 1) {
        if (threadIdx.x < off) red[threadIdx.x] += red[threadIdx.x + off];
        __syncthreads();
    }
    if (threadIdx.x == 0) blocksum[blockIdx.x] = red[0];
}

// ---------------------------------------------------------------------------
// Hierarchical scan phase B: exclusive scan of tile sums; rowptr[N]=E.
// ---------------------------------------------------------------------------
__global__ __launch_bounds__(1024) void scan_blocksum_kernel(
    int* __restrict__ blocksum, int nb, int* __restrict__ rowptr, int N, int E)
{
    __shared__ int part[1024];
    int t = threadIdx.x;
    part[t] = (t < nb) ? blocksum[t] : 0;
    __syncthreads();
    for (int off = 1; off < 1024; off <<= 1) {
        int v = (t >= off) ? part[t - off] : 0;
        __syncthreads();
        part[t] += v;
        __syncthreads();
    }
    if (t < nb) blocksum[t] = (t == 0) ? 0 : part[t - 1];  // exclusive
    if (t == 0) rowptr[N] = E;
}

// ---------------------------------------------------------------------------
// Hierarchical scan phase C: tile-local exclusive scan + tile offset;
// writes rowptr and scatter cursor (cursor aliases cnt).
// ---------------------------------------------------------------------------
__global__ __launch_bounds__(256) void scan_final_kernel(
    int* __restrict__ cnt, const int* __restrict__ blocksum,
    int* __restrict__ rowptr, int N)
{
    __shared__ int lds[SCAN_TILE];
    __shared__ int tsum[256];
    int base = blockIdx.x * SCAN_TILE;
    int tid = threadIdx.x;
#pragma unroll
    for (int k = 0; k < 8; ++k) {
        int i = base + k * 256 + tid;
        lds[k * 256 + tid] = (i < N) ? cnt[i] : 0;
    }
    __syncthreads();
    int my[8];
    int s = 0;
#pragma unroll
    for (int j = 0; j < 8; ++j) { my[j] = s; s += lds[tid * 8 + j]; }
    tsum[tid] = s;
    __syncthreads();
    for (int off = 1; off < 256; off <<= 1) {
        int v = (tid >= off) ? tsum[tid - off] : 0;
        __syncthreads();
        tsum[tid] += v;
        __syncthreads();
    }
    int texcl = (tid == 0) ? 0 : tsum[tid - 1];
    int boff = blocksum[blockIdx.x];
    __syncthreads();
#pragma unroll
    for (int j = 0; j < 8; ++j) lds[tid * 8 + j] = boff + texcl + my[j];
    __syncthreads();
#pragma unroll
    for (int k = 0; k < 8; ++k) {
        int i = base + k * 256 + tid;
        if (i < N) {
            int v = lds[k * 256 + tid];
            rowptr[i] = v;
            cnt[i] = v;      // scatter cursor
        }
    }
}

// ---------------------------------------------------------------------------
// CSR scatter: XCD-range-affine via b%8; per-node cursors (round-4 lesson:
// coarse cursors serialize). Plain loads: L3-served re-passes.
// ---------------------------------------------------------------------------
__global__ __launch_bounds__(256) void scatter_kernel(
    const int* __restrict__ ei, int* __restrict__ cursor,
    unsigned short* __restrict__ srclist, int E, int N, int nChunks)
{
    int b = blockIdx.x;
    int range = b & (NRANGE - 1);
    int chunk = b >> 3;
    int RS = (N + NRANGE - 1) / NRANGE;
    int lo = range * RS;
    unsigned span = (unsigned)(((lo + RS) > N ? N : (lo + RS)) - lo);
    int per = (E + nChunks - 1) / nChunks;
    int beg = chunk * per;
    int end = beg + per; if (end > E) end = E;
    for (int i = beg + (int)threadIdx.x; i < end; i += 256) {
        int dst = ei[E + i];
        if ((unsigned)(dst - lo) < span) {
            int src = ei[i];
            int pos = atomicAdd(&cursor[dst], 1);
            srclist[pos] = (unsigned short)src;
        }
    }
}

// ---------------------------------------------------------------------------
// GEMM1: h1 = x @ W1 ([N,64]x[64,64]) + fused alpha_src1/alpha_dst1.
// h1 stored fp16; alpha sums from fp32 acc.
// ---------------------------------------------------------------------------
__global__ __launch_bounds__(256) void gemm1_kernel(
    const float* __restrict__ x, const float* __restrict__ W,
    const float* __restrict__ a_src, const float* __restrict__ a_dst,
    __half* __restrict__ h1, float* __restrict__ as1, float* __restrict__ ad1,
    int N)
{
    __shared__ float Wl[64 * 64];
    __shared__ float Xl[4][64];
    int tid = threadIdx.x;
    for (int i = tid; i < 64 * 64; i += 256) Wl[i] = W[i];
    int r   = tid >> 6;
    int col = tid & 63;
    int row = blockIdx.x * 4 + r;
    if (row < N) Xl[r][col] = x[(size_t)row * 64 + col];
    __syncthreads();
    if (row >= N) return;

    float acc = 0.f;
#pragma unroll
    for (int k = 0; k < 64; ++k) acc += Xl[r][k] * Wl[k * 64 + col];
    h1[(size_t)row * 64 + col] = __float2half(acc);

    int head = col >> 5;
    float ps = acc * a_src[col];
    float pd = acc * a_dst[col];
#pragma unroll
    for (int off = 16; off; off >>= 1) {
        ps += __shfl_xor(ps, off, 32);
        pd += __shfl_xor(pd, off, 32);
    }
    if ((col & 31) == 0) {
        as1[row * 2 + head] = ps;
        ad1[row * 2 + head] = pd;
    }
}

// ---------------------------------------------------------------------------
// Fused layer-1 aggregation + GEMM2 + alpha2, 2-edge packed:
// lanes 0-31 = edge stream A, lanes 32-63 = edge stream B; each lane owns
// column pair (2*sub, 2*sub+1) via __half2 loads. One instruction stream per
// TWO edges (halves VALU cost). Self-loop = virtual edge index `deg`.
// Halves combined via shfl_xor(32); GEMM2 from per-wave LDS row as before.
// h2 written fp16.
// ---------------------------------------------------------------------------
__global__ __launch_bounds__(256) void agg1_gemm2_kernel(
    const int* __restrict__ rowptr, const unsigned short* __restrict__ srclist,
    const __half* __restrict__ h1, const float* __restrict__ as1,
    const float* __restrict__ ad1, const float* __restrict__ b1,
    const float* __restrict__ W2, const float* __restrict__ a_s2,
    const float* __restrict__ a_d2,
    __half* __restrict__ h2, float* __restrict__ as2, float* __restrict__ ad2,
    int N)
{
    __shared__ float W2l[64 * 32];
    __shared__ float sh[4][64];
    int tid = threadIdx.x;
    for (int i = tid; i < 64 * 32; i += 256) W2l[i] = W2[i];
    __syncthreads();   // block-uniform

    int n = (blockIdx.x * 256 + tid) >> 6;
    int lane = tid & 63;
    int wid = tid >> 6;
    if (n >= N) return;

    int eh   = lane >> 5;     // edge stream (0/1)
    int sub  = lane & 31;     // column pair index
    int head = sub >> 4;      // cols [0,32) head0, [32,64) head1
    float adn = ad1[n * 2 + head];
    const __half* h1base = h1 + 2 * sub;

    float accx = 0.f, accy = 0.f, den = 0.f;
    int beg = rowptr[n];
    int deg = rowptr[n + 1] - beg;
    int total = deg + 1;      // + self-loop (virtual index deg)
    int j = 0;
    for (; j + 3 < total; j += 4) {
        int e0 = j + eh, e1 = j + 2 + eh;
        int s0 = (e0 < deg) ? (int)srclist[beg + e0] : n;
        int s1 = (e1 < deg) ? (int)srclist[beg + e1] : n;
        float a0 = as1[s0 * 2 + head];
        float a1 = as1[s1 * 2 + head];
        float2 g0 = __half22float2(*(const __half2*)(h1base + (size_t)s0 * 64));
        float2 g1 = __half22float2(*(const __half2*)(h1base + (size_t)s1 * 64));
        float w0 = __expf(lrelu_f(a0 + adn));
        float w1 = __expf(lrelu_f(a1 + adn));
        den  += w0 + w1;
        accx += w0 * g0.x + w1 * g1.x;
        accy += w0 * g0.y + w1 * g1.y;
    }
    for (; j + 1 < total; j += 2) {
        int e = j + eh;
        int s = (e < deg) ? (int)srclist[beg + e] : n;
        float a = as1[s * 2 + head];
        float2 g = __half22float2(*(const __half2*)(h1base + (size_t)s * 64));
        float w = __expf(lrelu_f(a + adn));
        den += w; accx += w * g.x; accy += w * g.y;
    }
    if (j < total) {   // odd leftover: stream B masked
        int e = j;
        int s = (e < deg) ? (int)srclist[beg + e] : n;
        float a = as1[s * 2 + head];
        float2 g = __half22float2(*(const __half2*)(h1base + (size_t)s * 64));
        float w = eh ? 0.f : __expf(lrelu_f(a + adn));
        den += w; accx += w * g.x; accy += w * g.y;
    }
    accx += __shfl_xor(accx, 32, 64);
    accy += __shfl_xor(accy, 32, 64);
    den  += __shfl_xor(den, 32, 64);

    float2 bb = *(const float2*)(b1 + 2 * sub);
    float vx = elu_f(accx / den + bb.x);
    float vy = elu_f(accy / den + bb.y);
    if (eh == 0) ((float2*)sh[wid])[sub] = make_float2(vx, vy);
    // wave-internal LDS write->read: lgkmcnt ordering, same wave => coherent

    // ---- fused GEMM2: h2[n, col] = sum_k h1e[n,k] * W2[k, col] ----
    int col = lane & 31;
    int kbase = (lane >> 5) * 32;
    float p = 0.f;
#pragma unroll
    for (int jj = 0; jj < 32; ++jj)
        p += sh[wid][kbase + jj] * W2l[(kbase + jj) * 32 + col];
    p += __shfl_xor(p, 32, 64);

    if (lane < 32) h2[(size_t)n * 32 + lane] = __float2half(p);

    float ps = p * a_s2[col];
    float pd = p * a_d2[col];
#pragma unroll
    for (int off = 16; off; off >>= 1) {
        ps += __shfl_xor(ps, off, 32);
        pd += __shfl_xor(pd, off, 32);
    }
    if (lane == 0) { as2[n] = ps; ad2[n] = pd; }
}

// ---------------------------------------------------------------------------
// Layer-2 aggregation + final FC, 2-edge packed within each 32-lane node
// group: lanes [0,16) = edge stream A, [16,32) = stream B; each lane owns
// column pair (2*c2, 2*c2+1) via __half2 loads of fp16 h2.
// out layout: [0,N) scores, [N, N+N*32) h   (N even => float2 stores aligned)
// ---------------------------------------------------------------------------
__global__ __launch_bounds__(256) void agg2_kernel(
    const int* __restrict__ rowptr, const unsigned short* __restrict__ srclist,
    const __half* __restrict__ h2, const float* __restrict__ as2,
    const float* __restrict__ ad2, const float* __restrict__ b2,
    const float* __restrict__ fcW, const float* __restrict__ fcb,
    float* __restrict__ out, int N)
{
    int g = blockIdx.x * 256 + threadIdx.x;
    int n = g >> 5;
    if (n >= N) return;
    int sub = g & 31;
    int eh = sub >> 4;        // edge stream (0/1)
    int c2 = sub & 15;        // column pair index
    float adn = ad2[n];
    const __half* h2base = h2 + 2 * c2;

    float accx = 0.f, accy = 0.f, den = 0.f;
    int beg = rowptr[n];
    int deg = rowptr[n + 1] - beg;
    int total = deg + 1;
    int j = 0;
    for (; j + 3 < total; j += 4) {
        int e0 = j + eh, e1 = j + 2 + eh;
        int s0 = (e0 < deg) ? (int)srclist[beg + e0] : n;
        int s1 = (e1 < deg) ? (int)srclist[beg + e1] : n;
        float a0 = as2[s0], a1 = as2[s1];
        float2 g0 = __half22float2(*(const __half2*)(h2base + (size_t)s0 * 32));
        float2 g1 = __half22float2(*(const __half2*)(h2base + (size_t)s1 * 32));
        float w0 = __expf(lrelu_f(a0 + adn));
        float w1 = __expf(lrelu_f(a1 + adn));
        den  += w0 + w1;
        accx += w0 * g0.x + w1 * g1.x;
        accy += w0 * g0.y + w1 * g1.y;
    }
    for (; j + 1 < total; j += 2) {
        int e = j + eh;
        int s = (e < deg) ? (int)srclist[beg + e] : n;
        float a = as2[s];
        float2 g = __half22float2(*(const __half2*)(h2base + (size_t)s * 32));
        float w = __expf(lrelu_f(a + adn));
        den += w; accx += w * g.x; accy += w * g.y;
    }
    if (j < total) {
        int e = j;
        int s = (e < deg) ? (int)srclist[beg + e] : n;
        float a = as2[s];
        float2 g = __half22float2(*(const __half2*)(h2base + (size_t)s * 32));
        float w = eh ? 0.f : __expf(lrelu_f(a + adn));
        den += w; accx += w * g.x; accy += w * g.y;
    }
    accx += __shfl_xor(accx, 16, 64);
    accy += __shfl_xor(accy, 16, 64);
    den  += __shfl_xor(den, 16, 64);

    float2 bb = *(const float2*)(b2 + 2 * c2);
    float vx = elu_f(accx / den + bb.x);
    float vy = elu_f(accy / den + bb.y);
    if (eh == 0)
        ((float2*)(out + (size_t)N + (size_t)n * 32))[c2] = make_float2(vx, vy);

    float p = vx * fcW[2 * c2] + vy * fcW[2 * c2 + 1];
    p += __shfl_xor(p, 1, 64);
    p += __shfl_xor(p, 2, 64);
    p += __shfl_xor(p, 4, 64);
    p += __shfl_xor(p, 8, 64);
    if (sub == 0) out[n] = p + fcb[0];   // lane 0 of group: sum of lanes 0-15
}

extern "C" void kernel_launch(void* const* d_in, const int* in_sizes, int n_in,
                              void* d_out, int out_size, void* d_ws, size_t ws_size,
                              hipStream_t stream) {
    const float* x    = (const float*)d_in[0];
    const int*   ei   = (const int*)d_in[1];
    const float* W1   = (const float*)d_in[2];
    const float* a_s1 = (const float*)d_in[3];
    const float* a_d1 = (const float*)d_in[4];
    const float* b1   = (const float*)d_in[5];
    const float* W2   = (const float*)d_in[6];
    const float* a_s2 = (const float*)d_in[7];
    const float* a_d2 = (const float*)d_in[8];
    const float* b2   = (const float*)d_in[9];
    const float* fcW  = (const float*)d_in[10];
    const float* fcb  = (const float*)d_in[11];

    const int N = in_sizes[0] / 64;
    const int E = in_sizes[1] / 2;
    const int nScan = (N + SCAN_TILE - 1) / SCAN_TILE;

    // Workspace: fp32 arrays, then fp16 h2/h1, then ints, then ushort.
    float* fws  = (float*)d_ws;
    float* as1  = fws;                      // 2N
    float* ad1  = as1 + (size_t)2 * N;      // 2N
    float* as2  = ad1 + (size_t)2 * N;      // N
    float* ad2  = as2 + (size_t)N;          // N
    __half* h2  = (__half*)(ad2 + (size_t)N);       // 32N halves
    __half* h1  = h2 + (size_t)32 * N;              // 64N halves
    int*   cnt     = (int*)(h1 + (size_t)64 * N);   // N (histogram -> cursor)
    int*   rowptr  = cnt + N;                       // N+1
    int*   blocksum = rowptr + N + 1;               // nScan
    unsigned short* srclist = (unsigned short*)(blocksum + nScan);  // E

    hipMemsetAsync(cnt, 0, sizeof(int) * (size_t)N, stream);

    hist_kernel<<<(E + 255) / 256, 256, 0, stream>>>(ei, cnt, E);

    scan_partial_kernel<<<nScan, 256, 0, stream>>>(cnt, blocksum, N);
    scan_blocksum_kernel<<<1, 1024, 0, stream>>>(blocksum, nScan, rowptr, N, E);
    scan_final_kernel<<<nScan, 256, 0, stream>>>(cnt, blocksum, rowptr, N);

    const int nChunks = 256;  // 256 chunks x 8 ranges = 2048 scatter blocks
    scatter_kernel<<<nChunks * NRANGE, 256, 0, stream>>>(ei, cnt, srclist, E, N, nChunks);

    gemm1_kernel<<<(N + 3) / 4, 256, 0, stream>>>(x, W1, a_s1, a_d1, h1, as1, ad1, N);

    agg1_gemm2_kernel<<<((size_t)N * 64 + 255) / 256, 256, 0, stream>>>(
        rowptr, srclist, h1, as1, ad1, b1, W2, a_s2, a_d2, h2, as2, ad2, N);

    agg2_kernel<<<((size_t)N * 32 + 255) / 256, 256, 0, stream>>>(
        rowptr, srclist, h2, as2, ad2, b2, fcW, fcb, (float*)d_out, N);
}

// Round 10
// 340.884 us; speedup vs baseline: 1.1128x; 1.0867x over previous
//
#include <hip/hip_runtime.h>
#include <hip/hip_fp16.h>

#define NEG_SLOPE 0.2f
#define NRANGE 8          // dst-range partitions == XCD count (b%8 heuristic)
#define SCAN_TILE 2048    // elements per scan block

__device__ __forceinline__ float elu_f(float x) {
    return x > 0.f ? x : __expf(x) - 1.f;
}
__device__ __forceinline__ float lrelu_f(float x) {
    return fmaxf(x, NEG_SLOPE * x);
}

union H4 { float2 f2; __half2 h2[2]; };

// ---------------------------------------------------------------------------
// CSR build step 1: histogram of destination nodes. Plain loads: warms L3
// with ei so the scatter's 8 range-passes are L3-served (round-7 lesson).
// ---------------------------------------------------------------------------
__global__ __launch_bounds__(256) void hist_kernel(
    const int* __restrict__ ei, int* __restrict__ cnt, int E)
{
    int t = blockIdx.x * 256 + threadIdx.x;
    if (t < E) atomicAdd(&cnt[ei[E + t]], 1);
}

// ---------------------------------------------------------------------------
// Hierarchical scan phase A: per-tile sums.
// ---------------------------------------------------------------------------
__global__ __launch_bounds__(256) void scan_partial_kernel(
    const int* __restrict__ cnt, int* __restrict__ blocksum, int N)
{
    __shared__ int red[256];
    int base = blockIdx.x * SCAN_TILE;
    int s = 0;
#pragma unroll
    for (int k = 0; k < 8; ++k) {
        int i = base + k * 256 + threadIdx.x;
        if (i < N) s += cnt[i];
    }
    red[threadIdx.x] = s;
    __syncthreads();
    for (int off = 128; off; off >>= 1) {
        if (threadIdx.x < off) red[threadIdx.x] += red[threadIdx.x + off];
        __syncthreads();
    }
    if (threadIdx.x == 0) blocksum[blockIdx.x] = red[0];
}

// ---------------------------------------------------------------------------
// Hierarchical scan phase B: exclusive scan of tile sums; rowptr[N]=E.
// ---------------------------------------------------------------------------
__global__ __launch_bounds__(1024) void scan_blocksum_kernel(
    int* __restrict__ blocksum, int nb, int* __restrict__ rowptr, int N, int E)
{
    __shared__ int part[1024];
    int t = threadIdx.x;
    part[t] = (t < nb) ? blocksum[t] : 0;
    __syncthreads();
    for (int off = 1; off < 1024; off <<= 1) {
        int v = (t >= off) ? part[t - off] : 0;
        __syncthreads();
        part[t] += v;
        __syncthreads();
    }
    if (t < nb) blocksum[t] = (t == 0) ? 0 : part[t - 1];  // exclusive
    if (t == 0) rowptr[N] = E;
}

// ---------------------------------------------------------------------------
// Hierarchical scan phase C: tile-local exclusive scan + tile offset;
// writes rowptr and scatter cursor (cursor aliases cnt).
// ---------------------------------------------------------------------------
__global__ __launch_bounds__(256) void scan_final_kernel(
    int* __restrict__ cnt, const int* __restrict__ blocksum,
    int* __restrict__ rowptr, int N)
{
    __shared__ int lds[SCAN_TILE];
    __shared__ int tsum[256];
    int base = blockIdx.x * SCAN_TILE;
    int tid = threadIdx.x;
#pragma unroll
    for (int k = 0; k < 8; ++k) {
        int i = base + k * 256 + tid;
        lds[k * 256 + tid] = (i < N) ? cnt[i] : 0;
    }
    __syncthreads();
    int my[8];
    int s = 0;
#pragma unroll
    for (int j = 0; j < 8; ++j) { my[j] = s; s += lds[tid * 8 + j]; }
    tsum[tid] = s;
    __syncthreads();
    for (int off = 1; off < 256; off <<= 1) {
        int v = (tid >= off) ? tsum[tid - off] : 0;
        __syncthreads();
        tsum[tid] += v;
        __syncthreads();
    }
    int texcl = (tid == 0) ? 0 : tsum[tid - 1];
    int boff = blocksum[blockIdx.x];
    __syncthreads();
#pragma unroll
    for (int j = 0; j < 8; ++j) lds[tid * 8 + j] = boff + texcl + my[j];
    __syncthreads();
#pragma unroll
    for (int k = 0; k < 8; ++k) {
        int i = base + k * 256 + tid;
        if (i < N) {
            int v = lds[k * 256 + tid];
            rowptr[i] = v;
            cnt[i] = v;      // scatter cursor
        }
    }
}

// ---------------------------------------------------------------------------
// CSR scatter: XCD-range-affine via b%8; per-node cursors (round-4 lesson:
// coarse cursors serialize). Plain loads: L3-served re-passes.
// ---------------------------------------------------------------------------
__global__ __launch_bounds__(256) void scatter_kernel(
    const int* __restrict__ ei, int* __restrict__ cursor,
    unsigned short* __restrict__ srclist, int E, int N, int nChunks)
{
    int b = blockIdx.x;
    int range = b & (NRANGE - 1);
    int chunk = b >> 3;
    int RS = (N + NRANGE - 1) / NRANGE;
    int lo = range * RS;
    unsigned span = (unsigned)(((lo + RS) > N ? N : (lo + RS)) - lo);
    int per = (E + nChunks - 1) / nChunks;
    int beg = chunk * per;
    int end = beg + per; if (end > E) end = E;
    for (int i = beg + (int)threadIdx.x; i < end; i += 256) {
        int dst = ei[E + i];
        if ((unsigned)(dst - lo) < span) {
            int src = ei[i];
            int pos = atomicAdd(&cursor[dst], 1);
            srclist[pos] = (unsigned short)src;
        }
    }
}

// ---------------------------------------------------------------------------
// GEMM1: h1 = x @ W1 ([N,64]x[64,64]) + fused alpha_src1/alpha_dst1.
// h1 stored fp16; alpha sums from fp32 acc.
// ---------------------------------------------------------------------------
__global__ __launch_bounds__(256) void gemm1_kernel(
    const float* __restrict__ x, const float* __restrict__ W,
    const float* __restrict__ a_src, const float* __restrict__ a_dst,
    __half* __restrict__ h1, float* __restrict__ as1, float* __restrict__ ad1,
    int N)
{
    __shared__ float Wl[64 * 64];
    __shared__ float Xl[4][64];
    int tid = threadIdx.x;
    for (int i = tid; i < 64 * 64; i += 256) Wl[i] = W[i];
    int r   = tid >> 6;
    int col = tid & 63;
    int row = blockIdx.x * 4 + r;
    if (row < N) Xl[r][col] = x[(size_t)row * 64 + col];
    __syncthreads();
    if (row >= N) return;

    float acc = 0.f;
#pragma unroll
    for (int k = 0; k < 64; ++k) acc += Xl[r][k] * Wl[k * 64 + col];
    h1[(size_t)row * 64 + col] = __float2half(acc);

    int head = col >> 5;
    float ps = acc * a_src[col];
    float pd = acc * a_dst[col];
#pragma unroll
    for (int off = 16; off; off >>= 1) {
        ps += __shfl_xor(ps, off, 32);
        pd += __shfl_xor(pd, off, 32);
    }
    if ((col & 31) == 0) {
        as1[row * 2 + head] = ps;
        ad1[row * 2 + head] = pd;
    }
}

// ---------------------------------------------------------------------------
// Fused layer-1 aggregation + GEMM2 + alpha2, 4-edge packed with
// register-cached edge lists:
//  - per 64-edge chunk, lane i caches srclist[beg+i] (ONE coalesced load);
//    inner loop gets src via __shfl (no global latency in the chain).
//  - 4 groups x 16 lanes; each lane owns column quad 4*cl..4*cl+3 (8B load).
//  - 2x manual unroll (8 edges/iter, no masks needed: j+8<=cnt => valid).
//  - self-loop = virtual edge deg (lane li==deg caches es=n).
// Group combine via shfl_xor(16/32); head = cl>>3 so quads never cross heads.
// ---------------------------------------------------------------------------
__global__ __launch_bounds__(256) void agg1_gemm2_kernel(
    const int* __restrict__ rowptr, const unsigned short* __restrict__ srclist,
    const __half* __restrict__ h1, const float* __restrict__ as1,
    const float* __restrict__ ad1, const float* __restrict__ b1,
    const float* __restrict__ W2, const float* __restrict__ a_s2,
    const float* __restrict__ a_d2,
    __half* __restrict__ h2, float* __restrict__ as2, float* __restrict__ ad2,
    int N)
{
    __shared__ float W2l[64 * 32];
    __shared__ float sh[4][64];
    int tid = threadIdx.x;
    for (int i = tid; i < 64 * 32; i += 256) W2l[i] = W2[i];
    __syncthreads();   // block-uniform

    int n = (blockIdx.x * 256 + tid) >> 6;
    int lane = tid & 63;
    int wid = tid >> 6;
    if (n >= N) return;

    int grp = lane >> 4;      // edge group 0..3
    int cl  = lane & 15;      // column quad: cols 4cl..4cl+3
    int head = cl >> 3;       // quads 0-7 head0, 8-15 head1
    float adn = ad1[n * 2 + head];
    const __half* h1q = h1 + 4 * cl;

    float den = 0.f, a0 = 0.f, a1 = 0.f, a2 = 0.f, a3 = 0.f;

    int beg = rowptr[n];
    int deg = rowptr[n + 1] - beg;
    int total = deg + 1;      // + virtual self-loop at index deg

    for (int base = 0; base < total; base += 64) {
        int rem = total - base;
        int cnt = rem > 64 ? 64 : rem;
        int li = base + lane;
        int es = (li < deg) ? (int)srclist[beg + li] : n;  // cached edge srcs
        int j = 0;
        // unrolled: both 4-edge packs fully valid (j+8 <= cnt)
        for (; j + 8 <= cnt; j += 8) {
            int sA = __shfl(es, j + grp, 64);
            int sB = __shfl(es, j + 4 + grp, 64);
            float aA = as1[sA * 2 + head];
            float aB = as1[sB * 2 + head];
            H4 uA, uB;
            uA.f2 = *(const float2*)(h1q + (size_t)sA * 64);
            uB.f2 = *(const float2*)(h1q + (size_t)sB * 64);
            float wA = __expf(lrelu_f(aA + adn));
            float wB = __expf(lrelu_f(aB + adn));
            float2 gA01 = __half22float2(uA.h2[0]);
            float2 gA23 = __half22float2(uA.h2[1]);
            float2 gB01 = __half22float2(uB.h2[0]);
            float2 gB23 = __half22float2(uB.h2[1]);
            den += wA + wB;
            a0 += wA * gA01.x + wB * gB01.x;
            a1 += wA * gA01.y + wB * gB01.y;
            a2 += wA * gA23.x + wB * gB23.x;
            a3 += wA * gA23.y + wB * gB23.y;
        }
        for (; j < cnt; j += 4) {
            int e = j + grp;
            int s = __shfl(es, e & 63, 64);
            float a = as1[s * 2 + head];
            H4 u;
            u.f2 = *(const float2*)(h1q + (size_t)s * 64);
            float w = (e < rem) ? __expf(lrelu_f(a + adn)) : 0.f;
            float2 g01 = __half22float2(u.h2[0]);
            float2 g23 = __half22float2(u.h2[1]);
            den += w;
            a0 += w * g01.x; a1 += w * g01.y;
            a2 += w * g23.x; a3 += w * g23.y;
        }
    }
    // combine the 4 edge groups (flips grp bits; cl/head invariant)
    a0 += __shfl_xor(a0, 16, 64); a1 += __shfl_xor(a1, 16, 64);
    a2 += __shfl_xor(a2, 16, 64); a3 += __shfl_xor(a3, 16, 64);
    den += __shfl_xor(den, 16, 64);
    a0 += __shfl_xor(a0, 32, 64); a1 += __shfl_xor(a1, 32, 64);
    a2 += __shfl_xor(a2, 32, 64); a3 += __shfl_xor(a3, 32, 64);
    den += __shfl_xor(den, 32, 64);

    float4 bb = *(const float4*)(b1 + 4 * cl);
    float inv = 1.f / den;
    float v0 = elu_f(a0 * inv + bb.x);
    float v1 = elu_f(a1 * inv + bb.y);
    float v2 = elu_f(a2 * inv + bb.z);
    float v3 = elu_f(a3 * inv + bb.w);
    if (grp == 0) ((float4*)sh[wid])[cl] = make_float4(v0, v1, v2, v3);
    // wave-internal LDS write->read: DS ops in-order per wave => coherent

    // ---- fused GEMM2: h2[n, col] = sum_k h1e[n,k] * W2[k, col] ----
    int col = lane & 31;
    int kbase = (lane >> 5) * 32;
    float p = 0.f;
#pragma unroll
    for (int jj = 0; jj < 32; ++jj)
        p += sh[wid][kbase + jj] * W2l[(kbase + jj) * 32 + col];
    p += __shfl_xor(p, 32, 64);

    if (lane < 32) h2[(size_t)n * 32 + lane] = __float2half(p);

    float ps = p * a_s2[col];
    float pd = p * a_d2[col];
#pragma unroll
    for (int off = 16; off; off >>= 1) {
        ps += __shfl_xor(ps, off, 32);
        pd += __shfl_xor(pd, off, 32);
    }
    if (lane == 0) { as2[n] = ps; ad2[n] = pd; }
}

// ---------------------------------------------------------------------------
// Layer-2 aggregation + final FC, 4-edge packed, register-cached edge list.
// 32 lanes per node: 4 groups x 8 lanes, each lane owns column quad
// 4*cl..4*cl+3 of the 32-col fp16 h2 row (8B load). Chunks of 32 edges.
// out layout: [0,N) scores, [N, N+N*32) h   (requires N % 4 == 0 for float4)
// ---------------------------------------------------------------------------
__global__ __launch_bounds__(256) void agg2_kernel(
    const int* __restrict__ rowptr, const unsigned short* __restrict__ srclist,
    const __half* __restrict__ h2, const float* __restrict__ as2,
    const float* __restrict__ ad2, const float* __restrict__ b2,
    const float* __restrict__ fcW, const float* __restrict__ fcb,
    float* __restrict__ out, int N)
{
    int g = blockIdx.x * 256 + threadIdx.x;
    int n = g >> 5;
    if (n >= N) return;
    int l32 = g & 31;
    int grp = l32 >> 3;       // edge group 0..3
    int cl  = l32 & 7;        // column quad: cols 4cl..4cl+3
    float adn = ad2[n];
    const __half* h2q = h2 + 4 * cl;

    float den = 0.f, a0 = 0.f, a1 = 0.f, a2 = 0.f, a3 = 0.f;

    int beg = rowptr[n];
    int deg = rowptr[n + 1] - beg;
    int total = deg + 1;

    for (int base = 0; base < total; base += 32) {
        int rem = total - base;
        int cnt = rem > 32 ? 32 : rem;
        int li = base + l32;
        int es = (li < deg) ? (int)srclist[beg + li] : n;
        int j = 0;
        for (; j + 8 <= cnt; j += 8) {
            int sA = __shfl(es, j + grp, 32);
            int sB = __shfl(es, j + 4 + grp, 32);
            float aA = as2[sA];
            float aB = as2[sB];
            H4 uA, uB;
            uA.f2 = *(const float2*)(h2q + (size_t)sA * 32);
            uB.f2 = *(const float2*)(h2q + (size_t)sB * 32);
            float wA = __expf(lrelu_f(aA + adn));
            float wB = __expf(lrelu_f(aB + adn));
            float2 gA01 = __half22float2(uA.h2[0]);
            float2 gA23 = __half22float2(uA.h2[1]);
            float2 gB01 = __half22float2(uB.h2[0]);
            float2 gB23 = __half22float2(uB.h2[1]);
            den += wA + wB;
            a0 += wA * gA01.x + wB * gB01.x;
            a1 += wA * gA01.y + wB * gB01.y;
            a2 += wA * gA23.x + wB * gB23.x;
            a3 += wA * gA23.y + wB * gB23.y;
        }
        for (; j < cnt; j += 4) {
            int e = j + grp;
            int s = __shfl(es, e & 31, 32);
            float a = as2[s];
            H4 u;
            u.f2 = *(const float2*)(h2q + (size_t)s * 32);
            float w = (e < rem) ? __expf(lrelu_f(a + adn)) : 0.f;
            float2 g01 = __half22float2(u.h2[0]);
            float2 g23 = __half22float2(u.h2[1]);
            den += w;
            a0 += w * g01.x; a1 += w * g01.y;
            a2 += w * g23.x; a3 += w * g23.y;
        }
    }
    // combine 4 edge groups (xor 8,16 stay within the 32-lane node group)
    a0 += __shfl_xor(a0, 8, 64);  a1 += __shfl_xor(a1, 8, 64);
    a2 += __shfl_xor(a2, 8, 64);  a3 += __shfl_xor(a3, 8, 64);
    den += __shfl_xor(den, 8, 64);
    a0 += __shfl_xor(a0, 16, 64); a1 += __shfl_xor(a1, 16, 64);
    a2 += __shfl_xor(a2, 16, 64); a3 += __shfl_xor(a3, 16, 64);
    den += __shfl_xor(den, 16, 64);

    float4 bb = *(const float4*)(b2 + 4 * cl);
    float inv = 1.f / den;
    float v0 = elu_f(a0 * inv + bb.x);
    float v1 = elu_f(a1 * inv + bb.y);
    float v2 = elu_f(a2 * inv + bb.z);
    float v3 = elu_f(a3 * inv + bb.w);
    if (grp == 0)
        ((float4*)(out + (size_t)N + (size_t)n * 32))[cl] =
            make_float4(v0, v1, v2, v3);

    float4 fw = *(const float4*)(fcW + 4 * cl);
    float p = v0 * fw.x + v1 * fw.y + v2 * fw.z + v3 * fw.w;
    p += __shfl_xor(p, 1, 64);
    p += __shfl_xor(p, 2, 64);
    p += __shfl_xor(p, 4, 64);
    if (l32 == 0) out[n] = p + fcb[0];
}

extern "C" void kernel_launch(void* const* d_in, const int* in_sizes, int n_in,
                              void* d_out, int out_size, void* d_ws, size_t ws_size,
                              hipStream_t stream) {
    const float* x    = (const float*)d_in[0];
    const int*   ei   = (const int*)d_in[1];
    const float* W1   = (const float*)d_in[2];
    const float* a_s1 = (const float*)d_in[3];
    const float* a_d1 = (const float*)d_in[4];
    const float* b1   = (const float*)d_in[5];
    const float* W2   = (const float*)d_in[6];
    const float* a_s2 = (const float*)d_in[7];
    const float* a_d2 = (const float*)d_in[8];
    const float* b2   = (const float*)d_in[9];
    const float* fcW  = (const float*)d_in[10];
    const float* fcb  = (const float*)d_in[11];

    const int N = in_sizes[0] / 64;
    const int E = in_sizes[1] / 2;
    const int nScan = (N + SCAN_TILE - 1) / SCAN_TILE;

    // Workspace: fp32 arrays, then fp16 h2/h1, then ints, then ushort.
    float* fws  = (float*)d_ws;
    float* as1  = fws;                      // 2N
    float* ad1  = as1 + (size_t)2 * N;      // 2N
    float* as2  = ad1 + (size_t)2 * N;      // N
    float* ad2  = as2 + (size_t)N;          // N
    __half* h2  = (__half*)(ad2 + (size_t)N);       // 32N halves
    __half* h1  = h2 + (size_t)32 * N;              // 64N halves
    int*   cnt     = (int*)(h1 + (size_t)64 * N);   // N (histogram -> cursor)
    int*   rowptr  = cnt + N;                       // N+1
    int*   blocksum = rowptr + N + 1;               // nScan
    unsigned short* srclist = (unsigned short*)(blocksum + nScan);  // E

    hipMemsetAsync(cnt, 0, sizeof(int) * (size_t)N, stream);

    hist_kernel<<<(E + 255) / 256, 256, 0, stream>>>(ei, cnt, E);

    scan_partial_kernel<<<nScan, 256, 0, stream>>>(cnt, blocksum, N);
    scan_blocksum_kernel<<<1, 1024, 0, stream>>>(blocksum, nScan, rowptr, N, E);
    scan_final_kernel<<<nScan, 256, 0, stream>>>(cnt, blocksum, rowptr, N);

    const int nChunks = 256;  // 256 chunks x 8 ranges = 2048 scatter blocks
    scatter_kernel<<<nChunks * NRANGE, 256, 0, stream>>>(ei, cnt, srclist, E, N, nChunks);

    gemm1_kernel<<<(N + 3) / 4, 256, 0, stream>>>(x, W1, a_s1, a_d1, h1, as1, ad1, N);

    agg1_gemm2_kernel<<<((size_t)N * 64 + 255) / 256, 256, 0, stream>>>(
        rowptr, srclist, h1, as1, ad1, b1, W2, a_s2, a_d2, h2, as2, ad2, N);

    agg2_kernel<<<((size_t)N * 32 + 255) / 256, 256, 0, stream>>>(
        rowptr, srclist, h2, as2, ad2, b2, fcW, fcb, (float*)d_out, N);
}